// Round 9
// baseline (265.478 us; speedup 1.0000x reference)
//
#include <hip/hip_runtime.h>

// RK4 + low-rank Christoffel, R-space formulation, single fused P/M/F kernel:
//   prep_wu: Wb/Ub bf16 row-major + Wf/Uf fragment-major
//   prep_g:  Gf fragment-major, G[n][k] = (U W^T)[k][n] = dot(W[n],U[k])
//   fused (512 blocks x 1024 thr, 16 rows/block, 16 waves; LDS 16 KB):
//     [P] A0 = x W^T, B0 = v W^T, F~ = force W^T — per-wave 16-col R-slice,
//         A-frags loaded DIRECT from global f32 (no LDS, no barriers; 16-way
//         L1 row reuse), packed to bf16 in-reg; results stay in registers in
//         the exact M-phase distribution (D-layout row=l4*4+e, col=rn).
//     [M] 16 stages, f32 accumulators (r8 lesson: bf16 repack was pure VALU
//         waste at the 128-reg budget), dbuf 8 KB C-tile, 1 barrier/stage;
//         dead work skipped (s=3,k=3 GEMM; s=3 A/B updates).
//     [F] Sv/Sx -> ct LDS, Gv = Sv U, Gx = Sx U vs Uf, fused epilogue:
//         cv = v0 + 4dt f - (dt/6) Gv ; cx = x0 + 4dt v0 + 6dt^2 f - (dt^2/6) Gx

typedef __attribute__((ext_vector_type(8))) short bf16x8;
typedef __attribute__((ext_vector_type(4))) float f32x4;
typedef unsigned short us;

#define MFMA16 __builtin_amdgcn_mfma_f32_16x16x32_bf16

namespace {
constexpr int kB = 8192;
constexpr int kD = 1024;
constexpr int kR = 256;
constexpr int kBM = 16;          // rows per block
constexpr float kDt = 0.01f;
}

__device__ __forceinline__ us f2bf(float f) {
  union { float f; unsigned u; } w; w.f = f;
  unsigned u = w.u + (0x7FFFu + ((w.u >> 16) & 1u));  // RNE
  return (us)(u >> 16);
}
__device__ __forceinline__ float ftanh(float x) {
  float e = __expf(2.f * x);
  return 1.f - 2.f / (e + 1.f);
}
__device__ __forceinline__ bf16x8 pack8(float4 a, float4 b) {
  union { bf16x8 v; us s[8]; } u;
  u.s[0] = f2bf(a.x); u.s[1] = f2bf(a.y); u.s[2] = f2bf(a.z); u.s[3] = f2bf(a.w);
  u.s[4] = f2bf(b.x); u.s[5] = f2bf(b.y); u.s[6] = f2bf(b.z); u.s[7] = f2bf(b.w);
  return u.v;
}

// ---------------------------------------------------------------------------
// prep 1: Wb/Ub row-major bf16 (prep_g inputs) + Wf/Uf fragment-major.
// Fragment-major (mfma_f32_16x16x32_bf16 B-operand): frag is 512 contiguous us;
// within frag: idx = (((k>>3)&3)*16 | (n&15))*8 + (k&7).
__global__ void prep_wu(const float* __restrict__ U, const float* __restrict__ W,
                        us* __restrict__ Wb, us* __restrict__ Ub,
                        us* __restrict__ Wf, us* __restrict__ Uf) {
  int i = blockIdx.x * blockDim.x + threadIdx.x;
  if (i < kR * kD) {
    const int r = i >> 10, k = i & 1023;
    const us wb = f2bf(W[i]), ub = f2bf(U[i]);
    Wb[i] = wb; Ub[i] = ub;
    // Wf: B-frag of (rows x W^T): n = r (R-col), contraction = k (D); 32 ktiles
    Wf[(((size_t)(r >> 4) * 32 + (k >> 5)) << 9) +
       (((((k >> 3) & 3) << 4) | (r & 15)) << 3) + (k & 7)] = wb;
    // Uf: B-frag of (S x U): n = d = k, contraction = r (R); 8 ktiles
    Uf[(((size_t)(k >> 4) * 8 + (r >> 5)) << 9) +
       (((((r >> 3) & 3) << 4) | (k & 15)) << 3) + (r & 7)] = ub;
  }
}

// prep 2: Gf frag-major, G[n][k] = dot(W[n,:], U[k,:]). 64 blocks x 256 thr.
__global__ __launch_bounds__(256) void prep_g(const us* __restrict__ Wb,
                                              const us* __restrict__ Ub,
                                              us* __restrict__ Gf) {
  const int tid = threadIdx.x;
  const int w = tid >> 6, l = tid & 63;
  const int l15 = l & 15, l4 = l >> 4;
  const int n1 = (blockIdx.x >> 3) * 32 + (w >> 1) * 16;
  const int k1 = (blockIdx.x & 7) * 32 + (w & 1) * 16;
  f32x4 acc = {0.f, 0.f, 0.f, 0.f};
  const us* wp = Wb + (size_t)(n1 + l15) * kD + l4 * 8;
  const us* up = Ub + (size_t)(k1 + l15) * kD + l4 * 8;
#pragma unroll 8
  for (int kk = 0; kk < 32; ++kk) {
    bf16x8 aw = *(const bf16x8*)(wp + kk * 32);
    bf16x8 bu = *(const bf16x8*)(up + kk * 32);
    acc = MFMA16(aw, bu, acc, 0, 0, 0);
  }
#pragma unroll
  for (int j = 0; j < 4; ++j) {
    const int n = n1 + l4 * 4 + j, k = k1 + l15;
    Gf[(((size_t)(n >> 4) * 8 + (k >> 5)) << 9) +
       (((((k >> 3) & 3) << 4) | (n & 15)) << 3) + (k & 7)] = f2bf(acc[j]);
  }
}

// ---------------------------------------------------------------------------
// Fused P/M/F kernel. mfma_f32_16x16x32_bf16 layouts (m89-verified):
//   A: row=l&15, k=(l>>4)*8+j ; B: col=l&15, same k ; D: col=l&15, row=(l>>4)*4+reg
// LDS C-tile XOR-swizzled: 8-elem k-group g of row r stored at slot g^(r&7).
__global__ __launch_bounds__(1024, 4) void fused_kernel(
    const us* __restrict__ Wf, const us* __restrict__ Gf, const us* __restrict__ Uf,
    const float* __restrict__ xin, const float* __restrict__ vin,
    const float* __restrict__ force,
    float* __restrict__ cxo, float* __restrict__ cvo) {
  __shared__ __align__(16) us ct[2][kBM * kR];   // 2 x 8 KB

  const int tid = threadIdx.x;
  const int w = tid >> 6;        // wave 0..15 = owned 16-col R-slice
  const int l = tid & 63;
  const int l15 = l & 15;
  const int l4 = l >> 4;
  const int rs = l15 & 7;
  const int brow = blockIdx.x * kBM;
  const int rn = w * 16 + l15;
  const float dt = kDt;
  const f32x4 zero4 = {0.f, 0.f, 0.f, 0.f};

  // ==== P: A0 = x W^T, B0 = v W^T, F~ = force W^T (f32, direct-global A) ====
  f32x4 Aa = zero4, Ba = zero4, Fa = zero4;
  {
    const size_t rb = (size_t)(brow + l15) * kD + l4 * 8;
    const float* xr = xin + rb;
    const float* vr = vin + rb;
    const float* fr = force + rb;
    const us* wfp = Wf + ((size_t)(w * 32) << 9) + l * 8;
#pragma unroll 4
    for (int kk = 0; kk < 32; ++kk) {
      bf16x8 ax = pack8(*(const float4*)(xr + kk * 32), *(const float4*)(xr + kk * 32 + 4));
      bf16x8 av = pack8(*(const float4*)(vr + kk * 32), *(const float4*)(vr + kk * 32 + 4));
      bf16x8 af = pack8(*(const float4*)(fr + kk * 32), *(const float4*)(fr + kk * 32 + 4));
      bf16x8 bw = *(const bf16x8*)(wfp + ((size_t)kk << 9));
      Aa = MFMA16(ax, bw, Aa, 0, 0, 0);
      Ba = MFMA16(av, bw, Ba, 0, 0, 0);
      Fa = MFMA16(af, bw, Fa, 0, 0, 0);
    }
  }

  // ---- G-slice (this wave's 8 fragments) -> 32 VGPRs ----
  bf16x8 gfr[8];
  {
    const us* gfp = Gf + ((size_t)(w * 8) << 9) + l * 8;
#pragma unroll
    for (int kk = 0; kk < 8; ++kk)
      gfr[kk] = *(const bf16x8*)(gfp + ((size_t)kk << 9));
  }

  // ---- per-thread R-space state, all f32 (D-layout matches P output) ----
  float A[4], Bv[4], Fv[4], q[4], CS[4], PS[4], Sv[4], Sx[4];
#pragma unroll
  for (int e = 0; e < 4; ++e) {
    A[e] = Aa[e]; Bv[e] = Ba[e]; Fv[e] = Fa[e]; Sv[e] = 0.f; Sx[e] = 0.f;
  }

  // invariant swizzled LDS write offsets (row = l4*4+e, col = rn)
  int wo[4];
#pragma unroll
  for (int e = 0; e < 4; ++e) {
    const int r = l4 * 4 + e;
    wo[e] = (r << 8) + ((((rn >> 3) ^ (r & 7)) << 3) | (rn & 7));
  }

  // ==== M: 16 stages ====
#pragma unroll 1
  for (int s = 0; s < 4; ++s) {
#pragma unroll
    for (int e = 0; e < 4; ++e) { q[e] = Bv[e]; CS[e] = 0.f; PS[e] = 0.f; }

#pragma unroll
    for (int k = 0; k < 4; ++k) {
      const float alpha = (k == 0) ? 0.f : ((k == 3) ? dt : 0.5f * dt);
      const float wk = (k == 1 || k == 2) ? 2.f : 1.f;
      const float beta = (k <= 1) ? 0.5f * dt : dt;
      float c[4];
#pragma unroll
      for (int e = 0; e < 4; ++e) {
        const float hx = A[e] + alpha * Bv[e];
        c[e] = ftanh(hx) * q[e] * q[e];
        CS[e] += wk * c[e];
      }
      if (s == 3 && k == 3) break;   // P4 of last step only feeds dead Bv

      us* cb = ct[k & 1];
#pragma unroll
      for (int e = 0; e < 4; ++e) cb[wo[e]] = f2bf(c[e]);
      __syncthreads();

      f32x4 P = zero4;
#pragma unroll
      for (int kk = 0; kk < 8; ++kk) {
        bf16x8 ca = *(const bf16x8*)(cb + (l15 << 8) + (((kk * 4 + l4) ^ rs) << 3));
        P = MFMA16(ca, gfr[kk], P, 0, 0, 0);
      }
#pragma unroll
      for (int e = 0; e < 4; ++e) {
        PS[e] += wk * P[e];
        if (k < 3) q[e] = Bv[e] + beta * (Fv[e] - P[e]);
      }
    }

#pragma unroll
    for (int e = 0; e < 4; ++e) Sv[e] += CS[e];
    if (s < 3) {
      const float wsx = (float)(3 - s);
#pragma unroll
      for (int e = 0; e < 4; ++e) {
        Sx[e] += wsx * CS[e];
        A[e] += dt * Bv[e];                              // uses old B
        Bv[e] += dt * Fv[e] - (dt / 6.f) * PS[e];
      }
    }
  }

  // ==== F: Gv = Sv U, Gx = Sx U + epilogue ====
  __syncthreads();   // drain last stage's ct reads before overwrite
#pragma unroll
  for (int e = 0; e < 4; ++e) {
    ct[0][wo[e]] = f2bf(Sv[e]);
    ct[1][wo[e]] = f2bf(Sx[e]);
  }
  __syncthreads();

#pragma unroll 1
  for (int nt = 0; nt < 4; ++nt) {
    f32x4 gv = zero4, gx = zero4;
    const int d0 = w * 64 + nt * 16;
    const us* ufp = Uf + ((size_t)((d0 >> 4) * 8) << 9) + l * 8;
#pragma unroll
    for (int kk = 0; kk < 8; ++kk) {
      const int aoff = (l15 << 8) + (((kk * 4 + l4) ^ rs) << 3);
      bf16x8 ub = *(const bf16x8*)(ufp + ((size_t)kk << 9));
      gv = MFMA16(*(const bf16x8*)(ct[0] + aoff), ub, gv, 0, 0, 0);
      gx = MFMA16(*(const bf16x8*)(ct[1] + aoff), ub, gx, 0, 0, 0);
    }
#pragma unroll
    for (int j = 0; j < 4; ++j) {
      const int row = l4 * 4 + j;
      const size_t gi = (size_t)(brow + row) * kD + d0 + l15;
      const float x0 = xin[gi], v0 = vin[gi], f = force[gi];
      cxo[gi] = x0 + 4.f * dt * v0 + 6.f * dt * dt * f - (dt * dt / 6.f) * gx[j];
      cvo[gi] = v0 + 4.f * dt * f - (dt / 6.f) * gv[j];
    }
  }
}

// ---------------------------------------------------------------------------
__global__ void copy_only_kernel(const float* __restrict__ x, const float* __restrict__ v,
                                 float* __restrict__ cx, float* __restrict__ cv) {
  const int stride = gridDim.x * blockDim.x;
  for (int i = blockIdx.x * blockDim.x + threadIdx.x; i < kB * kD; i += stride) {
    cx[i] = x[i]; cv[i] = v[i];
  }
}

extern "C" void kernel_launch(void* const* d_in, const int* in_sizes, int n_in,
                              void* d_out, int out_size, void* d_ws, size_t ws_size,
                              hipStream_t stream) {
  const float* x = (const float*)d_in[0];
  const float* v = (const float*)d_in[1];
  const float* force = (const float*)d_in[2];
  const float* U = (const float*)d_in[3];
  const float* W = (const float*)d_in[4];
  // d_in[5] = steps (static 4 per reference)

  float* cx = (float*)d_out;
  float* cv = cx + (size_t)kB * kD;

  size_t off = 0;
  us* Wb = (us*)((char*)d_ws + off); off += (size_t)kR * kD * 2;
  us* Ub = (us*)((char*)d_ws + off); off += (size_t)kR * kD * 2;
  us* Wf = (us*)((char*)d_ws + off); off += (size_t)kR * kD * 2;
  us* Uf = (us*)((char*)d_ws + off); off += (size_t)kR * kD * 2;
  us* Gf = (us*)((char*)d_ws + off); off += (size_t)kR * kR * 2;

  if (ws_size < off) {
    copy_only_kernel<<<2048, 256, 0, stream>>>(x, v, cx, cv);
    return;
  }

  prep_wu<<<(kR * kD + 255) / 256, 256, 0, stream>>>(U, W, Wb, Ub, Wf, Uf);
  prep_g<<<64, 256, 0, stream>>>(Wb, Ub, Gf);
  fused_kernel<<<kB / kBM, 1024, 0, stream>>>(Wf, Gf, Uf, x, v, force, cx, cv);
}

// Round 10
// 131.078 us; speedup vs baseline: 2.0253x; 2.0253x over previous
//
#include <hip/hip_runtime.h>

// RK4 + low-rank Christoffel, R-space formulation, 3-phase split (r8 structure):
//   prep_wu: Wb/Ub bf16 row-major + Wf/Uf fragment-major
//   prep_g:  Gf fragment-major, G[n][k] = (U W^T)[k][n] = dot(W[n],U[k])
//   prep_abf (P): A0 = x W^T, B0 = v W^T, F~ = force W^T  (f32, 25 MB)
//     r10: single 24 KB staging buffer + launch_bounds(512,6) -> 3 blocks/CU
//   mid (M): 16-stage R-space loop; G-slice in 32 VGPRs/lane; dbuf C-tile
//     r10: all-f32 accumulators (bf16 repack was pure VALU waste) + dead-work
//     skip (s=3,k=3 GEMM/barrier; s=3 A/B updates). launch_bounds(1024,4)
//     (r7 lesson: (1024,8) spilled the G-slice -> 730 MB scratch traffic).
//   fin (F): Gv = Sv U, Gx = Sx U ;
//     cv = v0 + 4dt f - (dt/6) Gv ; cx = x0 + 4dt v0 + 6dt^2 f - (dt^2/6) Gx
// r9 lesson: do NOT read the row-tile direct-from-global per wave (16-way
// redundancy -> L1 overflow -> +175 MB L2/L3 refetch). Stage through LDS.

typedef __attribute__((ext_vector_type(8))) short bf16x8;
typedef __attribute__((ext_vector_type(4))) float f32x4;
typedef unsigned short us;

#define MFMA16 __builtin_amdgcn_mfma_f32_16x16x32_bf16

namespace {
constexpr int kB = 8192;
constexpr int kD = 1024;
constexpr int kR = 256;
constexpr int kBM = 16;          // rows per block
constexpr float kDt = 0.01f;
}

__device__ __forceinline__ us f2bf(float f) {
  union { float f; unsigned u; } w; w.f = f;
  unsigned u = w.u + (0x7FFFu + ((w.u >> 16) & 1u));  // RNE
  return (us)(u >> 16);
}
__device__ __forceinline__ float ftanh(float x) {
  float e = __expf(2.f * x);
  return 1.f - 2.f / (e + 1.f);
}
__device__ __forceinline__ bf16x8 pack8(float4 a, float4 b) {
  union { bf16x8 v; us s[8]; } u;
  u.s[0] = f2bf(a.x); u.s[1] = f2bf(a.y); u.s[2] = f2bf(a.z); u.s[3] = f2bf(a.w);
  u.s[4] = f2bf(b.x); u.s[5] = f2bf(b.y); u.s[6] = f2bf(b.z); u.s[7] = f2bf(b.w);
  return u.v;
}

// ---------------------------------------------------------------------------
// prep 1: Wb/Ub row-major bf16 (prep_g inputs) + Wf/Uf fragment-major.
// Fragment-major (mfma_f32_16x16x32_bf16 B-operand): frag is 512 contiguous us;
// within frag: idx = (((k>>3)&3)*16 | (n&15))*8 + (k&7).
__global__ void prep_wu(const float* __restrict__ U, const float* __restrict__ W,
                        us* __restrict__ Wb, us* __restrict__ Ub,
                        us* __restrict__ Wf, us* __restrict__ Uf) {
  int i = blockIdx.x * blockDim.x + threadIdx.x;
  if (i < kR * kD) {
    const int r = i >> 10, k = i & 1023;
    const us wb = f2bf(W[i]), ub = f2bf(U[i]);
    Wb[i] = wb; Ub[i] = ub;
    // Wf: B-frag of (rows x W^T): n = r (R-col), contraction = k (D); 32 ktiles
    Wf[(((size_t)(r >> 4) * 32 + (k >> 5)) << 9) +
       (((((k >> 3) & 3) << 4) | (r & 15)) << 3) + (k & 7)] = wb;
    // Uf: B-frag of (S x U): n = d = k, contraction = r (R); 8 ktiles
    Uf[(((size_t)(k >> 4) * 8 + (r >> 5)) << 9) +
       (((((r >> 3) & 3) << 4) | (k & 15)) << 3) + (r & 7)] = ub;
  }
}

// prep 2: Gf frag-major, G[n][k] = dot(W[n,:], U[k,:]). 64 blocks x 256 thr.
__global__ __launch_bounds__(256) void prep_g(const us* __restrict__ Wb,
                                              const us* __restrict__ Ub,
                                              us* __restrict__ Gf) {
  const int tid = threadIdx.x;
  const int w = tid >> 6, l = tid & 63;
  const int l15 = l & 15, l4 = l >> 4;
  const int n1 = (blockIdx.x >> 3) * 32 + (w >> 1) * 16;
  const int k1 = (blockIdx.x & 7) * 32 + (w & 1) * 16;
  f32x4 acc = {0.f, 0.f, 0.f, 0.f};
  const us* wp = Wb + (size_t)(n1 + l15) * kD + l4 * 8;
  const us* up = Ub + (size_t)(k1 + l15) * kD + l4 * 8;
#pragma unroll 8
  for (int kk = 0; kk < 32; ++kk) {
    bf16x8 aw = *(const bf16x8*)(wp + kk * 32);
    bf16x8 bu = *(const bf16x8*)(up + kk * 32);
    acc = MFMA16(aw, bu, acc, 0, 0, 0);
  }
#pragma unroll
  for (int j = 0; j < 4; ++j) {
    const int n = n1 + l4 * 4 + j, k = k1 + l15;
    Gf[(((size_t)(n >> 4) * 8 + (k >> 5)) << 9) +
       (((((k >> 3) & 3) << 4) | (n & 15)) << 3) + (k & 7)] = f2bf(acc[j]);
  }
}

// ---------------------------------------------------------------------------
// P: A0 = x W^T, B0 = v W^T, F~ = force W^T (f32). 512 blocks x 512 thr.
// Single 24 KB LDS staging buffer, 2 barriers/chunk, JIT loads issued before
// barrier-1 (latency hides under the sync). launch_bounds(512,6) -> 3 blk/CU.
__global__ __launch_bounds__(512, 6) void prep_abf(
    const us* __restrict__ Wf,
    const float* __restrict__ xin, const float* __restrict__ vin,
    const float* __restrict__ force,
    float* __restrict__ A0, float* __restrict__ B0, float* __restrict__ F0) {
  __shared__ __align__(16) us stg[12288];   // {x,v,f}[16][256] bf16 swizzled

  const int tid = threadIdx.x;
  const int w = tid >> 6, l = tid & 63;
  const int l15 = l & 15, l4 = l >> 4;
  const int rs = l15 & 7;
  const int brow = blockIdx.x * kBM;
  const int n0 = w * 32;
  const f32x4 zero4 = {0.f, 0.f, 0.f, 0.f};
  f32x4 Aa[2], Ba[2], Fa[2];
  Aa[0] = zero4; Aa[1] = zero4; Ba[0] = zero4; Ba[1] = zero4;
  Fa[0] = zero4; Fa[1] = zero4;

  const int row = tid >> 5, c8 = tid & 31;
  const int so = (row << 8) + ((c8 ^ (row & 7)) << 3);
  const size_t gb0 = (size_t)(brow + row) * kD + c8 * 8;

#pragma unroll 1
  for (int ch = 0; ch < 4; ++ch) {
    // JIT loads for this chunk (issued before barrier-1; latency overlaps sync)
    const size_t gb = gb0 + (size_t)ch * 256;
    float4 xr0 = *(const float4*)(xin + gb),  xr1 = *(const float4*)(xin + gb + 4);
    float4 vr0 = *(const float4*)(vin + gb),  vr1 = *(const float4*)(vin + gb + 4);
    float4 fr0 = *(const float4*)(force + gb), fr1 = *(const float4*)(force + gb + 4);
    if (ch) __syncthreads();            // all waves done READING previous chunk
    *(bf16x8*)(stg + so) = pack8(xr0, xr1);
    *(bf16x8*)(stg + 4096 + so) = pack8(vr0, vr1);
    *(bf16x8*)(stg + 8192 + so) = pack8(fr0, fr1);
    __syncthreads();                    // staging ready
#pragma unroll
    for (int kk = 0; kk < 8; ++kk) {
      const int aoff = (l15 << 8) + ((((kk * 4 + l4)) ^ rs) << 3);
      bf16x8 ax = *(const bf16x8*)(stg + aoff);
      bf16x8 av = *(const bf16x8*)(stg + 4096 + aoff);
      bf16x8 af = *(const bf16x8*)(stg + 8192 + aoff);
#pragma unroll
      for (int nt = 0; nt < 2; ++nt) {
        bf16x8 bw = *(const bf16x8*)(Wf +
            (((size_t)((w * 2 + nt) * 32 + ch * 8 + kk)) << 9) + l * 8);
        Aa[nt] = MFMA16(ax, bw, Aa[nt], 0, 0, 0);
        Ba[nt] = MFMA16(av, bw, Ba[nt], 0, 0, 0);
        Fa[nt] = MFMA16(af, bw, Fa[nt], 0, 0, 0);
      }
    }
  }
#pragma unroll
  for (int nt = 0; nt < 2; ++nt)
#pragma unroll
    for (int j = 0; j < 4; ++j) {
      const size_t o = (size_t)(brow + l4 * 4 + j) * kR + n0 + nt * 16 + l15;
      A0[o] = Aa[nt][j]; B0[o] = Ba[nt][j]; F0[o] = Fa[nt][j];
    }
}

// ---------------------------------------------------------------------------
// M: 16-stage R-space loop. 512 blocks x 1024 thr; G-slice in registers.
// All-f32 accumulators; dead s=3,k=3 GEMM and s=3 A/B updates skipped.
__global__ __launch_bounds__(1024, 4) void mid_kernel(
    const us* __restrict__ Gf,
    const float* __restrict__ A0, const float* __restrict__ B0,
    const float* __restrict__ F0,
    us* __restrict__ Svg, us* __restrict__ Sxg) {
  __shared__ __align__(16) us ct[2][kBM * kR];   // 2 x 8 KB C-tiles

  const int tid = threadIdx.x;
  const int w = tid >> 6;        // wave 0..15
  const int l = tid & 63;
  const int l15 = l & 15;
  const int l4 = l >> 4;
  const int rs = l15 & 7;
  const int brow = blockIdx.x * kBM;
  const int rn = w * 16 + l15;   // owned R-space column
  const float dt = kDt;
  const f32x4 zero4 = {0.f, 0.f, 0.f, 0.f};

  // G-slice (this wave's 8 fragments) -> 32 VGPRs
  bf16x8 gfr[8];
  {
    const us* gfp = Gf + ((size_t)(w * 8) << 9) + l * 8;
#pragma unroll
    for (int kk = 0; kk < 8; ++kk)
      gfr[kk] = *(const bf16x8*)(gfp + ((size_t)kk << 9));
  }

  float A[4], Bv[4], Fv[4], q[4], CS[4], PS[4], Sv[4], Sx[4];
#pragma unroll
  for (int e = 0; e < 4; ++e) {
    const size_t o = (size_t)(brow + l4 * 4 + e) * kR + rn;
    A[e] = A0[o]; Bv[e] = B0[o]; Fv[e] = F0[o];
    Sv[e] = 0.f; Sx[e] = 0.f;
  }

  // invariant swizzled LDS write offsets (row = l4*4+e, col = rn)
  int wo[4];
#pragma unroll
  for (int e = 0; e < 4; ++e) {
    const int r = l4 * 4 + e;
    wo[e] = (r << 8) + ((((rn >> 3) ^ (r & 7)) << 3) | (rn & 7));
  }

#pragma unroll 1
  for (int s = 0; s < 4; ++s) {
#pragma unroll
    for (int e = 0; e < 4; ++e) { q[e] = Bv[e]; CS[e] = 0.f; PS[e] = 0.f; }

#pragma unroll
    for (int k = 0; k < 4; ++k) {
      const float alpha = (k == 0) ? 0.f : ((k == 3) ? dt : 0.5f * dt);
      const float wk = (k == 1 || k == 2) ? 2.f : 1.f;
      const float beta = (k <= 1) ? 0.5f * dt : dt;
      float c[4];
#pragma unroll
      for (int e = 0; e < 4; ++e) {
        const float hx = A[e] + alpha * Bv[e];
        c[e] = ftanh(hx) * q[e] * q[e];
        CS[e] += wk * c[e];
      }
      if (s == 3 && k == 3) break;   // P4 of last step only feeds dead Bv

      us* cb = ct[k & 1];
#pragma unroll
      for (int e = 0; e < 4; ++e) cb[wo[e]] = f2bf(c[e]);
      __syncthreads();

      f32x4 P = zero4;
#pragma unroll
      for (int kk = 0; kk < 8; ++kk) {
        bf16x8 ca = *(const bf16x8*)(cb + (l15 << 8) + (((kk * 4 + l4) ^ rs) << 3));
        P = MFMA16(ca, gfr[kk], P, 0, 0, 0);
      }
#pragma unroll
      for (int e = 0; e < 4; ++e) {
        PS[e] += wk * P[e];
        if (k < 3) q[e] = Bv[e] + beta * (Fv[e] - P[e]);
      }
    }

#pragma unroll
    for (int e = 0; e < 4; ++e) Sv[e] += CS[e];
    if (s < 3) {
      const float wsx = (float)(3 - s);
#pragma unroll
      for (int e = 0; e < 4; ++e) {
        Sx[e] += wsx * CS[e];
        A[e] += dt * Bv[e];                              // uses old B
        Bv[e] += dt * Fv[e] - (dt / 6.f) * PS[e];
      }
    }
  }

  // write Sv/Sx (bf16 row-major [8192][256])
#pragma unroll
  for (int e = 0; e < 4; ++e) {
    const int r = l4 * 4 + e;
    Svg[(size_t)(brow + r) * kR + rn] = f2bf(Sv[e]);
    Sxg[(size_t)(brow + r) * kR + rn] = f2bf(Sx[e]);
  }
}

// ---------------------------------------------------------------------------
// F: Gv = Sv U, Gx = Sx U + epilogue. 512 blocks x 512 thr.
__global__ __launch_bounds__(512) void fin_kernel(
    const us* __restrict__ Uf, const us* __restrict__ Svg, const us* __restrict__ Sxg,
    const float* __restrict__ xin, const float* __restrict__ vin,
    const float* __restrict__ force,
    float* __restrict__ cxo, float* __restrict__ cvo) {
  __shared__ __align__(16) us svL[kBM * kR], sxL[kBM * kR];   // 8 KB + 8 KB

  const int tid = threadIdx.x;
  const int w = tid >> 6, l = tid & 63;
  const int l15 = l & 15, l4 = l >> 4;
  const int rs = l15 & 7;
  const int brow = blockIdx.x * kBM;
  const float dt = kDt;
  const f32x4 zero4 = {0.f, 0.f, 0.f, 0.f};

  {
    const int row = tid >> 5, grp = tid & 31;
    const int so = (row << 8) + ((grp ^ (row & 7)) << 3);
    *(bf16x8*)(svL + so) = *(const bf16x8*)(Svg + (size_t)(brow + row) * kR + grp * 8);
    *(bf16x8*)(sxL + so) = *(const bf16x8*)(Sxg + (size_t)(brow + row) * kR + grp * 8);
  }
  __syncthreads();

#pragma unroll 1
  for (int nt = 0; nt < 8; ++nt) {
    const int d0 = w * 128 + nt * 16;
    f32x4 gv = zero4, gx = zero4;
    const us* ufp = Uf + ((size_t)((d0 >> 4) * 8) << 9) + l * 8;
#pragma unroll
    for (int kk = 0; kk < 8; ++kk) {
      const int aoff = (l15 << 8) + (((kk * 4 + l4) ^ rs) << 3);
      bf16x8 ub = *(const bf16x8*)(ufp + ((size_t)kk << 9));
      gv = MFMA16(*(const bf16x8*)(svL + aoff), ub, gv, 0, 0, 0);
      gx = MFMA16(*(const bf16x8*)(sxL + aoff), ub, gx, 0, 0, 0);
    }
#pragma unroll
    for (int j = 0; j < 4; ++j) {
      const int row = l4 * 4 + j;
      const size_t gi = (size_t)(brow + row) * kD + d0 + l15;
      const float x0 = xin[gi], v0 = vin[gi], f = force[gi];
      cxo[gi] = x0 + 4.f * dt * v0 + 6.f * dt * dt * f - (dt * dt / 6.f) * gx[j];
      cvo[gi] = v0 + 4.f * dt * f - (dt / 6.f) * gv[j];
    }
  }
}

// ---------------------------------------------------------------------------
__global__ void copy_only_kernel(const float* __restrict__ x, const float* __restrict__ v,
                                 float* __restrict__ cx, float* __restrict__ cv) {
  const int stride = gridDim.x * blockDim.x;
  for (int i = blockIdx.x * blockDim.x + threadIdx.x; i < kB * kD; i += stride) {
    cx[i] = x[i]; cv[i] = v[i];
  }
}

extern "C" void kernel_launch(void* const* d_in, const int* in_sizes, int n_in,
                              void* d_out, int out_size, void* d_ws, size_t ws_size,
                              hipStream_t stream) {
  const float* x = (const float*)d_in[0];
  const float* v = (const float*)d_in[1];
  const float* force = (const float*)d_in[2];
  const float* U = (const float*)d_in[3];
  const float* W = (const float*)d_in[4];
  // d_in[5] = steps (static 4 per reference)

  float* cx = (float*)d_out;
  float* cv = cx + (size_t)kB * kD;

  size_t off = 0;
  us* Wb = (us*)((char*)d_ws + off); off += (size_t)kR * kD * 2;
  us* Ub = (us*)((char*)d_ws + off); off += (size_t)kR * kD * 2;
  us* Wf = (us*)((char*)d_ws + off); off += (size_t)kR * kD * 2;
  us* Uf = (us*)((char*)d_ws + off); off += (size_t)kR * kD * 2;
  us* Gf = (us*)((char*)d_ws + off); off += (size_t)kR * kR * 2;
  float* A0 = (float*)((char*)d_ws + off); off += (size_t)kB * kR * 4;
  float* B0 = (float*)((char*)d_ws + off); off += (size_t)kB * kR * 4;
  float* F0 = (float*)((char*)d_ws + off); off += (size_t)kB * kR * 4;
  us* Svg = (us*)((char*)d_ws + off); off += (size_t)kB * kR * 2;
  us* Sxg = (us*)((char*)d_ws + off); off += (size_t)kB * kR * 2;

  if (ws_size < off) {
    copy_only_kernel<<<2048, 256, 0, stream>>>(x, v, cx, cv);
    return;
  }

  prep_wu<<<(kR * kD + 255) / 256, 256, 0, stream>>>(U, W, Wb, Ub, Wf, Uf);
  prep_g<<<64, 256, 0, stream>>>(Wb, Ub, Gf);
  prep_abf<<<kB / kBM, 512, 0, stream>>>(Wf, x, v, force, A0, B0, F0);
  mid_kernel<<<kB / kBM, 1024, 0, stream>>>(Gf, A0, B0, F0, Svg, Sxg);
  fin_kernel<<<kB / kBM, 512, 0, stream>>>(Uf, Svg, Sxg, x, v, force, cx, cv);
}

// Round 11
// 117.452 us; speedup vs baseline: 2.2603x; 1.1160x over previous
//
#include <hip/hip_runtime.h>

// RK4 + low-rank Christoffel, R-space formulation, single fused P/M/F kernel.
//   prep_wu: Wb/Ub bf16 row-major + Wf/Uf fragment-major
//   prep_g:  Gf fragment-major, G[n][k] = (U W^T)[k][n] = dot(W[n],U[k])
//   fused (512 blocks x 1024 thr = 16 waves, launch_bounds(1024,4) = 128 regs):
//     [P] A = x W^T, B = v W^T, F~ = force W^T. x/v/force staged through LDS
//         (r9 lesson: direct-global per-wave reads = 16x redundancy = +175 MB).
//         16 waves, each owns one 16-col rn-slice -> 1 Wf frag per kk,
//         software-pipelined (r10 lesson: VGPR-starved loads serialize; the
//         128-reg budget + depth-1 prefetch keeps L2 latency hidden).
//         Output lands in registers in the exact M distribution.
//     [M] 16 stages, f32 accumulators, dbuf 8 KB C-tile, 1 barrier/stage,
//         G-slice in 32 VGPRs (r7 lesson: never let it spill), dead-work skip
//         (s=3,k=3 GEMM/barrier; s=3 A/B updates).
//     [F] Sv/Sx -> ct LDS; Gv = Sv U, Gx = Sx U vs Uf; fused epilogue:
//         cv = v0 + 4dt f - (dt/6) Gv ; cx = x0 + 4dt v0 + 6dt^2 f - (dt^2/6) Gx
//   No A0/B0/F0 or Svg/Sxg round-trips, no inter-phase kernel boundaries.

typedef __attribute__((ext_vector_type(8))) short bf16x8;
typedef __attribute__((ext_vector_type(4))) float f32x4;
typedef unsigned short us;

#define MFMA16 __builtin_amdgcn_mfma_f32_16x16x32_bf16

namespace {
constexpr int kB = 8192;
constexpr int kD = 1024;
constexpr int kR = 256;
constexpr int kBM = 16;          // rows per block
constexpr float kDt = 0.01f;
}

__device__ __forceinline__ us f2bf(float f) {
  union { float f; unsigned u; } w; w.f = f;
  unsigned u = w.u + (0x7FFFu + ((w.u >> 16) & 1u));  // RNE
  return (us)(u >> 16);
}
__device__ __forceinline__ float ftanh(float x) {
  float e = __expf(2.f * x);
  return 1.f - 2.f / (e + 1.f);
}
__device__ __forceinline__ bf16x8 pack8(float4 a, float4 b) {
  union { bf16x8 v; us s[8]; } u;
  u.s[0] = f2bf(a.x); u.s[1] = f2bf(a.y); u.s[2] = f2bf(a.z); u.s[3] = f2bf(a.w);
  u.s[4] = f2bf(b.x); u.s[5] = f2bf(b.y); u.s[6] = f2bf(b.z); u.s[7] = f2bf(b.w);
  return u.v;
}

// ---------------------------------------------------------------------------
// prep 1: Wb/Ub row-major bf16 (prep_g inputs) + Wf/Uf fragment-major.
// Fragment-major (mfma_f32_16x16x32_bf16 B-operand): frag is 512 contiguous us;
// within frag: idx = (((k>>3)&3)*16 | (n&15))*8 + (k&7).
__global__ void prep_wu(const float* __restrict__ U, const float* __restrict__ W,
                        us* __restrict__ Wb, us* __restrict__ Ub,
                        us* __restrict__ Wf, us* __restrict__ Uf) {
  int i = blockIdx.x * blockDim.x + threadIdx.x;
  if (i < kR * kD) {
    const int r = i >> 10, k = i & 1023;
    const us wb = f2bf(W[i]), ub = f2bf(U[i]);
    Wb[i] = wb; Ub[i] = ub;
    // Wf: B-frag of (rows x W^T): n = r (R-col), contraction = k (D); 32 ktiles
    Wf[(((size_t)(r >> 4) * 32 + (k >> 5)) << 9) +
       (((((k >> 3) & 3) << 4) | (r & 15)) << 3) + (k & 7)] = wb;
    // Uf: B-frag of (S x U): n = d = k, contraction = r (R); 8 ktiles
    Uf[(((size_t)(k >> 4) * 8 + (r >> 5)) << 9) +
       (((((r >> 3) & 3) << 4) | (k & 15)) << 3) + (r & 7)] = ub;
  }
}

// prep 2: Gf frag-major, G[n][k] = dot(W[n,:], U[k,:]). 64 blocks x 256 thr.
__global__ __launch_bounds__(256) void prep_g(const us* __restrict__ Wb,
                                              const us* __restrict__ Ub,
                                              us* __restrict__ Gf) {
  const int tid = threadIdx.x;
  const int w = tid >> 6, l = tid & 63;
  const int l15 = l & 15, l4 = l >> 4;
  const int n1 = (blockIdx.x >> 3) * 32 + (w >> 1) * 16;
  const int k1 = (blockIdx.x & 7) * 32 + (w & 1) * 16;
  f32x4 acc = {0.f, 0.f, 0.f, 0.f};
  const us* wp = Wb + (size_t)(n1 + l15) * kD + l4 * 8;
  const us* up = Ub + (size_t)(k1 + l15) * kD + l4 * 8;
#pragma unroll 8
  for (int kk = 0; kk < 32; ++kk) {
    bf16x8 aw = *(const bf16x8*)(wp + kk * 32);
    bf16x8 bu = *(const bf16x8*)(up + kk * 32);
    acc = MFMA16(aw, bu, acc, 0, 0, 0);
  }
#pragma unroll
  for (int j = 0; j < 4; ++j) {
    const int n = n1 + l4 * 4 + j, k = k1 + l15;
    Gf[(((size_t)(n >> 4) * 8 + (k >> 5)) << 9) +
       (((((k >> 3) & 3) << 4) | (n & 15)) << 3) + (k & 7)] = f2bf(acc[j]);
  }
}

// ---------------------------------------------------------------------------
// Fused P/M/F kernel. mfma_f32_16x16x32_bf16 layouts (m89-verified):
//   A: row=l&15, k=(l>>4)*8+j ; B: col=l&15, same k ; D: col=l&15, row=(l>>4)*4+reg
// LDS bf16 tiles XOR-swizzled: 8-elem k-group g of row r stored at slot g^(r&7).
__global__ __launch_bounds__(1024, 4) void fused_kernel(
    const us* __restrict__ Wf, const us* __restrict__ Gf, const us* __restrict__ Uf,
    const float* __restrict__ xin, const float* __restrict__ vin,
    const float* __restrict__ force,
    float* __restrict__ cxo, float* __restrict__ cvo) {
  __shared__ __align__(16) us stg[12288];        // P: {x,v,f}[16][256] bf16, 24 KB
  __shared__ __align__(16) us ct[2][kBM * kR];   // M/F: 2 x 8 KB C-tiles

  const int tid = threadIdx.x;
  const int w = tid >> 6;        // wave 0..15 = owned 16-col R-slice
  const int l = tid & 63;
  const int l15 = l & 15;
  const int l4 = l >> 4;
  const int rs = l15 & 7;
  const int brow = blockIdx.x * kBM;
  const int rn = w * 16 + l15;
  const float dt = kDt;
  const f32x4 zero4 = {0.f, 0.f, 0.f, 0.f};

  // staging task map: task A (all tids): arr = tid>>9 (0=x,1=v), slot = tid&511;
  // task B (tid<512): force, same slot.
  const int slotA = tid & 511;
  const int rowA = slotA >> 5, grpA = slotA & 31;
  const int soA = (rowA << 8) + ((grpA ^ (rowA & 7)) << 3);
  us* dstA = stg + ((tid >> 9) << 12);
  const float* srcA = (tid >> 9) ? vin : xin;
  const size_t gbA0 = (size_t)(brow + rowA) * kD + grpA * 8;

  // ==== P: A = x W^T, B = v W^T, F~ = force W^T (f32 accum) ====
  f32x4 Aa = zero4, Ba = zero4, Fa = zero4;
#pragma unroll 1
  for (int ch = 0; ch < 4; ++ch) {
    // JIT loads (issued before the barrier; latency overlaps the sync)
    const size_t gb = gbA0 + (size_t)ch * 256;
    float4 a0 = *(const float4*)(srcA + gb), a1 = *(const float4*)(srcA + gb + 4);
    float4 b0, b1;
    if (tid < 512) { b0 = *(const float4*)(force + gb); b1 = *(const float4*)(force + gb + 4); }
    if (ch) __syncthreads();            // all waves done reading previous chunk
    *(bf16x8*)(dstA + soA) = pack8(a0, a1);
    if (tid < 512) *(bf16x8*)(stg + 8192 + soA) = pack8(b0, b1);
    __syncthreads();                    // staging ready

    const us* wfp = Wf + (((size_t)(w * 32 + ch * 8)) << 9) + l * 8;
    bf16x8 bw = *(const bf16x8*)(wfp);  // depth-1 Wf pipeline
#pragma unroll
    for (int kk = 0; kk < 8; ++kk) {
      const bf16x8 bwc = bw;
      if (kk < 7) bw = *(const bf16x8*)(wfp + (((size_t)(kk + 1)) << 9));
      const int aoff = (l15 << 8) + (((kk * 4 + l4) ^ rs) << 3);
      bf16x8 ax = *(const bf16x8*)(stg + aoff);
      bf16x8 av = *(const bf16x8*)(stg + 4096 + aoff);
      bf16x8 af = *(const bf16x8*)(stg + 8192 + aoff);
      Aa = MFMA16(ax, bwc, Aa, 0, 0, 0);
      Ba = MFMA16(av, bwc, Ba, 0, 0, 0);
      Fa = MFMA16(af, bwc, Fa, 0, 0, 0);
    }
  }

  // ---- G-slice (this wave's 8 fragments) -> 32 VGPRs ----
  bf16x8 gfr[8];
  {
    const us* gfp = Gf + ((size_t)(w * 8) << 9) + l * 8;
#pragma unroll
    for (int kk = 0; kk < 8; ++kk)
      gfr[kk] = *(const bf16x8*)(gfp + ((size_t)kk << 9));
  }

  // ---- per-thread R-space state, all f32 (D-layout matches P output) ----
  float A[4], Bv[4], Fv[4], q[4], CS[4], PS[4], Sv[4], Sx[4];
#pragma unroll
  for (int e = 0; e < 4; ++e) {
    A[e] = Aa[e]; Bv[e] = Ba[e]; Fv[e] = Fa[e]; Sv[e] = 0.f; Sx[e] = 0.f;
  }

  // invariant swizzled LDS write offsets (row = l4*4+e, col = rn)
  int wo[4];
#pragma unroll
  for (int e = 0; e < 4; ++e) {
    const int r = l4 * 4 + e;
    wo[e] = (r << 8) + ((((rn >> 3) ^ (r & 7)) << 3) | (rn & 7));
  }

  // ==== M: 16 stages ====
  __syncthreads();   // P staging reads done before ct overlays... (distinct LDS; kept for wave phase alignment)
#pragma unroll 1
  for (int s = 0; s < 4; ++s) {
#pragma unroll
    for (int e = 0; e < 4; ++e) { q[e] = Bv[e]; CS[e] = 0.f; PS[e] = 0.f; }

#pragma unroll
    for (int k = 0; k < 4; ++k) {
      const float alpha = (k == 0) ? 0.f : ((k == 3) ? dt : 0.5f * dt);
      const float wk = (k == 1 || k == 2) ? 2.f : 1.f;
      const float beta = (k <= 1) ? 0.5f * dt : dt;
      float c[4];
#pragma unroll
      for (int e = 0; e < 4; ++e) {
        const float hx = A[e] + alpha * Bv[e];
        c[e] = ftanh(hx) * q[e] * q[e];
        CS[e] += wk * c[e];
      }
      if (s == 3 && k == 3) break;   // P4 of last step only feeds dead Bv

      us* cb = ct[k & 1];
#pragma unroll
      for (int e = 0; e < 4; ++e) cb[wo[e]] = f2bf(c[e]);
      __syncthreads();

      f32x4 P = zero4;
#pragma unroll
      for (int kk = 0; kk < 8; ++kk) {
        bf16x8 ca = *(const bf16x8*)(cb + (l15 << 8) + (((kk * 4 + l4) ^ rs) << 3));
        P = MFMA16(ca, gfr[kk], P, 0, 0, 0);
      }
#pragma unroll
      for (int e = 0; e < 4; ++e) {
        PS[e] += wk * P[e];
        if (k < 3) q[e] = Bv[e] + beta * (Fv[e] - P[e]);
      }
    }

#pragma unroll
    for (int e = 0; e < 4; ++e) Sv[e] += CS[e];
    if (s < 3) {
      const float wsx = (float)(3 - s);
#pragma unroll
      for (int e = 0; e < 4; ++e) {
        Sx[e] += wsx * CS[e];
        A[e] += dt * Bv[e];                              // uses old B
        Bv[e] += dt * Fv[e] - (dt / 6.f) * PS[e];
      }
    }
  }

  // ==== F: Gv = Sv U, Gx = Sx U + epilogue ====
  __syncthreads();   // drain last stage's ct reads before overwrite
#pragma unroll
  for (int e = 0; e < 4; ++e) {
    ct[0][wo[e]] = f2bf(Sv[e]);
    ct[1][wo[e]] = f2bf(Sx[e]);
  }
  __syncthreads();

#pragma unroll 1
  for (int nt = 0; nt < 4; ++nt) {
    f32x4 gv = zero4, gx = zero4;
    const int d0 = w * 64 + nt * 16;
    const us* ufp = Uf + ((size_t)((w * 4 + nt) * 8) << 9) + l * 8;
#pragma unroll
    for (int kk = 0; kk < 8; ++kk) {
      const int aoff = (l15 << 8) + (((kk * 4 + l4) ^ rs) << 3);
      bf16x8 ub = *(const bf16x8*)(ufp + ((size_t)kk << 9));
      gv = MFMA16(*(const bf16x8*)(ct[0] + aoff), ub, gv, 0, 0, 0);
      gx = MFMA16(*(const bf16x8*)(ct[1] + aoff), ub, gx, 0, 0, 0);
    }
#pragma unroll
    for (int j = 0; j < 4; ++j) {
      const int row = l4 * 4 + j;
      const size_t gi = (size_t)(brow + row) * kD + d0 + l15;
      const float x0 = xin[gi], v0 = vin[gi], f = force[gi];
      cxo[gi] = x0 + 4.f * dt * v0 + 6.f * dt * dt * f - (dt * dt / 6.f) * gx[j];
      cvo[gi] = v0 + 4.f * dt * f - (dt / 6.f) * gv[j];
    }
  }
}

// ---------------------------------------------------------------------------
__global__ void copy_only_kernel(const float* __restrict__ x, const float* __restrict__ v,
                                 float* __restrict__ cx, float* __restrict__ cv) {
  const int stride = gridDim.x * blockDim.x;
  for (int i = blockIdx.x * blockDim.x + threadIdx.x; i < kB * kD; i += stride) {
    cx[i] = x[i]; cv[i] = v[i];
  }
}

extern "C" void kernel_launch(void* const* d_in, const int* in_sizes, int n_in,
                              void* d_out, int out_size, void* d_ws, size_t ws_size,
                              hipStream_t stream) {
  const float* x = (const float*)d_in[0];
  const float* v = (const float*)d_in[1];
  const float* force = (const float*)d_in[2];
  const float* U = (const float*)d_in[3];
  const float* W = (const float*)d_in[4];
  // d_in[5] = steps (static 4 per reference)

  float* cx = (float*)d_out;
  float* cv = cx + (size_t)kB * kD;

  size_t off = 0;
  us* Wb = (us*)((char*)d_ws + off); off += (size_t)kR * kD * 2;
  us* Ub = (us*)((char*)d_ws + off); off += (size_t)kR * kD * 2;
  us* Wf = (us*)((char*)d_ws + off); off += (size_t)kR * kD * 2;
  us* Uf = (us*)((char*)d_ws + off); off += (size_t)kR * kD * 2;
  us* Gf = (us*)((char*)d_ws + off); off += (size_t)kR * kR * 2;

  if (ws_size < off) {
    copy_only_kernel<<<2048, 256, 0, stream>>>(x, v, cx, cv);
    return;
  }

  prep_wu<<<(kR * kD + 255) / 256, 256, 0, stream>>>(U, W, Wb, Ub, Wf, Uf);
  prep_g<<<64, 256, 0, stream>>>(Wb, Ub, Gf);
  fused_kernel<<<kB / kBM, 1024, 0, stream>>>(Wf, Gf, Uf, x, v, force, cx, cv);
}

// Round 12
// 113.761 us; speedup vs baseline: 2.3337x; 1.0324x over previous
//
#include <hip/hip_runtime.h>
#include <hip/hip_bf16.h>

// RK4 + low-rank Christoffel, R-space formulation, single fused P/M/F kernel.
//   prep_wu: Wb/Ub bf16 row-major + Wf/Uf fragment-major
//   prep_g:  Gf fragment-major, G[n][k] = (U W^T)[k][n] = dot(W[n],U[k])
//   fused (512 blocks x 1024 thr = 16 waves, launch_bounds(1024,4)):
//     [P] A = x W^T, B = v W^T, F~ = force W^T. x/v/force staged through
//         DOUBLE-BUFFERED LDS bf16 (2x24 KB); chunk ch+1's global loads are
//         issued right after chunk ch's staging-ready barrier, hiding HBM
//         latency under ch's 24 MFMAs (T14). 3 float4/thread in flight.
//         (r9 lesson: no direct-global per-wave reads; r10 lesson: loads need
//         reg headroom to stay in flight.)
//     [M] 16 stages, f32 accumulators, dbuf 8 KB C-tile, 1 barrier/stage,
//         G-slice in 32 VGPRs (r7 lesson: never let it spill), dead-work skip.
//     [F] Sv/Sx -> ct LDS; Gv = Sv U, Gx = Sx U vs Uf; fused epilogue.
//   r12: all f32->bf16 conversions via v_cvt_pk_bf16_f32 (HW RNE), not manual
//   bit-twiddle — same rounding, ~1/6 the VALU ops.

typedef __attribute__((ext_vector_type(8))) short bf16x8;
typedef __attribute__((ext_vector_type(4))) short bf16x4;
typedef __attribute__((ext_vector_type(4))) float f32x4;
typedef unsigned short us;

#define MFMA16 __builtin_amdgcn_mfma_f32_16x16x32_bf16

namespace {
constexpr int kB = 8192;
constexpr int kD = 1024;
constexpr int kR = 256;
constexpr int kBM = 16;          // rows per block
constexpr float kDt = 0.01f;
}

__device__ __forceinline__ us f2bf(float f) {
  __hip_bfloat16 h = __float2bfloat16(f);           // HW cvt, RNE
  union { __hip_bfloat16 b; us u; } c; c.b = h;
  return c.u;
}
__device__ __forceinline__ bf16x4 pack4(float4 a) {
  union { bf16x4 v; __hip_bfloat162 h[2]; } u;
  u.h[0] = __float22bfloat162_rn(float2{a.x, a.y}); // v_cvt_pk_bf16_f32
  u.h[1] = __float22bfloat162_rn(float2{a.z, a.w});
  return u.v;
}
__device__ __forceinline__ float ftanh(float x) {
  float e = __expf(2.f * x);
  return 1.f - 2.f / (e + 1.f);
}

// ---------------------------------------------------------------------------
// prep 1: Wb/Ub row-major bf16 (prep_g inputs) + Wf/Uf fragment-major.
// Fragment-major (mfma_f32_16x16x32_bf16 B-operand): frag is 512 contiguous us;
// within frag: idx = (((k>>3)&3)*16 | (n&15))*8 + (k&7).
__global__ void prep_wu(const float* __restrict__ U, const float* __restrict__ W,
                        us* __restrict__ Wb, us* __restrict__ Ub,
                        us* __restrict__ Wf, us* __restrict__ Uf) {
  int i = blockIdx.x * blockDim.x + threadIdx.x;
  if (i < kR * kD) {
    const int r = i >> 10, k = i & 1023;
    const us wb = f2bf(W[i]), ub = f2bf(U[i]);
    Wb[i] = wb; Ub[i] = ub;
    // Wf: B-frag of (rows x W^T): n = r (R-col), contraction = k (D); 32 ktiles
    Wf[(((size_t)(r >> 4) * 32 + (k >> 5)) << 9) +
       (((((k >> 3) & 3) << 4) | (r & 15)) << 3) + (k & 7)] = wb;
    // Uf: B-frag of (S x U): n = d = k, contraction = r (R); 8 ktiles
    Uf[(((size_t)(k >> 4) * 8 + (r >> 5)) << 9) +
       (((((r >> 3) & 3) << 4) | (k & 15)) << 3) + (r & 7)] = ub;
  }
}

// prep 2: Gf frag-major, G[n][k] = dot(W[n,:], U[k,:]). 64 blocks x 256 thr.
__global__ __launch_bounds__(256) void prep_g(const us* __restrict__ Wb,
                                              const us* __restrict__ Ub,
                                              us* __restrict__ Gf) {
  const int tid = threadIdx.x;
  const int w = tid >> 6, l = tid & 63;
  const int l15 = l & 15, l4 = l >> 4;
  const int n1 = (blockIdx.x >> 3) * 32 + (w >> 1) * 16;
  const int k1 = (blockIdx.x & 7) * 32 + (w & 1) * 16;
  f32x4 acc = {0.f, 0.f, 0.f, 0.f};
  const us* wp = Wb + (size_t)(n1 + l15) * kD + l4 * 8;
  const us* up = Ub + (size_t)(k1 + l15) * kD + l4 * 8;
#pragma unroll 8
  for (int kk = 0; kk < 32; ++kk) {
    bf16x8 aw = *(const bf16x8*)(wp + kk * 32);
    bf16x8 bu = *(const bf16x8*)(up + kk * 32);
    acc = MFMA16(aw, bu, acc, 0, 0, 0);
  }
#pragma unroll
  for (int j = 0; j < 4; ++j) {
    const int n = n1 + l4 * 4 + j, k = k1 + l15;
    Gf[(((size_t)(n >> 4) * 8 + (k >> 5)) << 9) +
       (((((k >> 3) & 3) << 4) | (n & 15)) << 3) + (k & 7)] = f2bf(acc[j]);
  }
}

// ---------------------------------------------------------------------------
// Fused P/M/F kernel. mfma_f32_16x16x32_bf16 layouts (m89-verified):
//   A: row=l&15, k=(l>>4)*8+j ; B: col=l&15, same k ; D: col=l&15, row=(l>>4)*4+reg
// LDS bf16 tiles XOR-swizzled: 8-elem k-group g of row r stored at slot g^(r&7).
__global__ __launch_bounds__(1024, 4) void fused_kernel(
    const us* __restrict__ Wf, const us* __restrict__ Gf, const us* __restrict__ Uf,
    const float* __restrict__ xin, const float* __restrict__ vin,
    const float* __restrict__ force,
    float* __restrict__ cxo, float* __restrict__ cvo) {
  __shared__ __align__(16) us stg[24576];        // P: 2 x {x,v,f}[16][256] bf16
  __shared__ __align__(16) us ct[2][kBM * kR];   // M/F: 2 x 8 KB C-tiles

  const int tid = threadIdx.x;
  const int w = tid >> 6;        // wave 0..15 = owned 16-col R-slice
  const int l = tid & 63;
  const int l15 = l & 15;
  const int l4 = l >> 4;
  const int rs = l15 & 7;
  const int brow = blockIdx.x * kBM;
  const int rn = w * 16 + l15;
  const float dt = kDt;
  const f32x4 zero4 = {0.f, 0.f, 0.f, 0.f};

  // P staging map: thread -> (row = tid>>6, 4-f32 column group (tid&63)*4),
  // one float4 per array per chunk (balanced 3 float4/thread in flight).
  const int prow = tid >> 6;
  const int pg = (tid & 63) >> 1;          // 8-us group 0..31
  const int pso = (prow << 8) + ((pg ^ (prow & 7)) << 3) + (tid & 1) * 4;
  const size_t pgb0 = (size_t)(brow + prow) * kD + (tid & 63) * 4;

  // ==== P: A = x W^T, B = v W^T, F~ = force W^T (f32 accum) ====
  f32x4 Aa = zero4, Ba = zero4, Fa = zero4;
  {
    float4 xr = *(const float4*)(xin + pgb0);
    float4 vr = *(const float4*)(vin + pgb0);
    float4 fr = *(const float4*)(force + pgb0);
#pragma unroll 1
    for (int ch = 0; ch < 4; ++ch) {
      us* sb = stg + (ch & 1) * 12288;
      *(bf16x4*)(sb + pso) = pack4(xr);          // waits vmcnt for this chunk
      *(bf16x4*)(sb + 4096 + pso) = pack4(vr);
      *(bf16x4*)(sb + 8192 + pso) = pack4(fr);
      __syncthreads();                           // staging ready
      if (ch < 3) {                              // T14: issue next-chunk loads;
        const size_t gb = pgb0 + (size_t)(ch + 1) * 256;   // latency hides
        xr = *(const float4*)(xin + gb);                   // under MFMA below
        vr = *(const float4*)(vin + gb);
        fr = *(const float4*)(force + gb);
      }
      const us* wfp = Wf + (((size_t)(w * 32 + ch * 8)) << 9) + l * 8;
      bf16x8 bw = *(const bf16x8*)(wfp);         // depth-1 Wf pipeline
#pragma unroll
      for (int kk = 0; kk < 8; ++kk) {
        const bf16x8 bwc = bw;
        if (kk < 7) bw = *(const bf16x8*)(wfp + (((size_t)(kk + 1)) << 9));
        const int aoff = (l15 << 8) + (((kk * 4 + l4) ^ rs) << 3);
        bf16x8 ax = *(const bf16x8*)(sb + aoff);
        bf16x8 av = *(const bf16x8*)(sb + 4096 + aoff);
        bf16x8 af = *(const bf16x8*)(sb + 8192 + aoff);
        Aa = MFMA16(ax, bwc, Aa, 0, 0, 0);
        Ba = MFMA16(av, bwc, Ba, 0, 0, 0);
        Fa = MFMA16(af, bwc, Fa, 0, 0, 0);
      }
      // next iter writes the OTHER buffer; its readers (MFMA ch-1) completed
      // before this iter's barrier -> exactly 1 barrier per chunk
    }
  }

  // ---- G-slice (this wave's 8 fragments) -> 32 VGPRs ----
  bf16x8 gfr[8];
  {
    const us* gfp = Gf + ((size_t)(w * 8) << 9) + l * 8;
#pragma unroll
    for (int kk = 0; kk < 8; ++kk)
      gfr[kk] = *(const bf16x8*)(gfp + ((size_t)kk << 9));
  }

  // ---- per-thread R-space state, all f32 (D-layout matches P output) ----
  float A[4], Bv[4], Fv[4], q[4], CS[4], PS[4], Sv[4], Sx[4];
#pragma unroll
  for (int e = 0; e < 4; ++e) {
    A[e] = Aa[e]; Bv[e] = Ba[e]; Fv[e] = Fa[e]; Sv[e] = 0.f; Sx[e] = 0.f;
  }

  // invariant swizzled LDS write offsets (row = l4*4+e, col = rn)
  int wo[4];
#pragma unroll
  for (int e = 0; e < 4; ++e) {
    const int r = l4 * 4 + e;
    wo[e] = (r << 8) + ((((rn >> 3) ^ (r & 7)) << 3) | (rn & 7));
  }

  // ==== M: 16 stages (ct region disjoint from stg; no barrier needed here) ====
#pragma unroll 1
  for (int s = 0; s < 4; ++s) {
#pragma unroll
    for (int e = 0; e < 4; ++e) { q[e] = Bv[e]; CS[e] = 0.f; PS[e] = 0.f; }

#pragma unroll
    for (int k = 0; k < 4; ++k) {
      const float alpha = (k == 0) ? 0.f : ((k == 3) ? dt : 0.5f * dt);
      const float wk = (k == 1 || k == 2) ? 2.f : 1.f;
      const float beta = (k <= 1) ? 0.5f * dt : dt;
      float c[4];
#pragma unroll
      for (int e = 0; e < 4; ++e) {
        const float hx = A[e] + alpha * Bv[e];
        c[e] = ftanh(hx) * q[e] * q[e];
        CS[e] += wk * c[e];
      }
      if (s == 3 && k == 3) break;   // P4 of last step only feeds dead Bv

      us* cb = ct[k & 1];
#pragma unroll
      for (int e = 0; e < 4; ++e) cb[wo[e]] = f2bf(c[e]);
      __syncthreads();

      f32x4 P = zero4;
#pragma unroll
      for (int kk = 0; kk < 8; ++kk) {
        bf16x8 ca = *(const bf16x8*)(cb + (l15 << 8) + (((kk * 4 + l4) ^ rs) << 3));
        P = MFMA16(ca, gfr[kk], P, 0, 0, 0);
      }
#pragma unroll
      for (int e = 0; e < 4; ++e) {
        PS[e] += wk * P[e];
        if (k < 3) q[e] = Bv[e] + beta * (Fv[e] - P[e]);
      }
    }

#pragma unroll
    for (int e = 0; e < 4; ++e) Sv[e] += CS[e];
    if (s < 3) {
      const float wsx = (float)(3 - s);
#pragma unroll
      for (int e = 0; e < 4; ++e) {
        Sx[e] += wsx * CS[e];
        A[e] += dt * Bv[e];                              // uses old B
        Bv[e] += dt * Fv[e] - (dt / 6.f) * PS[e];
      }
    }
  }

  // ==== F: Gv = Sv U, Gx = Sx U + epilogue ====
  __syncthreads();   // drain last stage's ct reads before overwrite
#pragma unroll
  for (int e = 0; e < 4; ++e) {
    ct[0][wo[e]] = f2bf(Sv[e]);
    ct[1][wo[e]] = f2bf(Sx[e]);
  }
  __syncthreads();

#pragma unroll 1
  for (int nt = 0; nt < 4; ++nt) {
    f32x4 gv = zero4, gx = zero4;
    const int d0 = w * 64 + nt * 16;
    const us* ufp = Uf + ((size_t)((w * 4 + nt) * 8) << 9) + l * 8;
#pragma unroll
    for (int kk = 0; kk < 8; ++kk) {
      const int aoff = (l15 << 8) + (((kk * 4 + l4) ^ rs) << 3);
      bf16x8 ub = *(const bf16x8*)(ufp + ((size_t)kk << 9));
      gv = MFMA16(*(const bf16x8*)(ct[0] + aoff), ub, gv, 0, 0, 0);
      gx = MFMA16(*(const bf16x8*)(ct[1] + aoff), ub, gx, 0, 0, 0);
    }
#pragma unroll
    for (int j = 0; j < 4; ++j) {
      const int row = l4 * 4 + j;
      const size_t gi = (size_t)(brow + row) * kD + d0 + l15;
      const float x0 = xin[gi], v0 = vin[gi], f = force[gi];
      cxo[gi] = x0 + 4.f * dt * v0 + 6.f * dt * dt * f - (dt * dt / 6.f) * gx[j];
      cvo[gi] = v0 + 4.f * dt * f - (dt / 6.f) * gv[j];
    }
  }
}

// ---------------------------------------------------------------------------
__global__ void copy_only_kernel(const float* __restrict__ x, const float* __restrict__ v,
                                 float* __restrict__ cx, float* __restrict__ cv) {
  const int stride = gridDim.x * blockDim.x;
  for (int i = blockIdx.x * blockDim.x + threadIdx.x; i < kB * kD; i += stride) {
    cx[i] = x[i]; cv[i] = v[i];
  }
}

extern "C" void kernel_launch(void* const* d_in, const int* in_sizes, int n_in,
                              void* d_out, int out_size, void* d_ws, size_t ws_size,
                              hipStream_t stream) {
  const float* x = (const float*)d_in[0];
  const float* v = (const float*)d_in[1];
  const float* force = (const float*)d_in[2];
  const float* U = (const float*)d_in[3];
  const float* W = (const float*)d_in[4];
  // d_in[5] = steps (static 4 per reference)

  float* cx = (float*)d_out;
  float* cv = cx + (size_t)kB * kD;

  size_t off = 0;
  us* Wb = (us*)((char*)d_ws + off); off += (size_t)kR * kD * 2;
  us* Ub = (us*)((char*)d_ws + off); off += (size_t)kR * kD * 2;
  us* Wf = (us*)((char*)d_ws + off); off += (size_t)kR * kD * 2;
  us* Uf = (us*)((char*)d_ws + off); off += (size_t)kR * kD * 2;
  us* Gf = (us*)((char*)d_ws + off); off += (size_t)kR * kR * 2;

  if (ws_size < off) {
    copy_only_kernel<<<2048, 256, 0, stream>>>(x, v, cx, cv);
    return;
  }

  prep_wu<<<(kR * kD + 255) / 256, 256, 0, stream>>>(U, W, Wb, Ub, Wf, Uf);
  prep_g<<<64, 256, 0, stream>>>(Wb, Ub, Gf);
  fused_kernel<<<kB / kBM, 1024, 0, stream>>>(Wf, Gf, Uf, x, v, force, cx, cv);
}